// Round 9
// baseline (317.221 us; speedup 1.0000x reference)
//
#include <hip/hip_runtime.h>
#include <hip/hip_cooperative_groups.h>
#include <math.h>

#define N_NODES 25000
#define N_EDGES 400000
#define EMBED   128
#define HEADS   8
#define DK      16
#define MAXDEG  96        // Poisson(16) max over 25000 nodes ~ 45; 96 is ultra-safe
#define NX (N_NODES * 128)
#define GBLK 391                         // ceil(25000/64) GEMM row-blocks
#define SCAT_BLK 391                     // ceil(400000/(256*4)) scatter blocks
#define TOT_BLK (3 * GBLK + SCAT_BLK)    // 1564 virtual blocks, phase 1
#define ATTN_VB (N_NODES / 4)            // 6250 virtual blocks, phase 2

namespace cg = cooperative_groups;

typedef __attribute__((ext_vector_type(8))) short bf16x8;
typedef __attribute__((ext_vector_type(4))) float f32x4;
typedef unsigned int uint;
typedef unsigned short ushort;

__device__ inline uint pack2_bf16(float a, float b) {
    union { float f; uint u; } ua, ub;
    ua.f = a; ub.f = b;
    uint ra = (ua.u + 0x7FFFu + ((ua.u >> 16) & 1u)) >> 16;
    uint rb = (ub.u + 0x7FFFu + ((ub.u >> 16) & 1u)) >> 16;
    return (ra & 0xFFFFu) | (rb << 16);
}
__device__ inline ushort cvt_bf16(float a) {
    union { float f; uint u; } ua; ua.f = a;
    return (ushort)((ua.u + 0x7FFFu + ((ua.u >> 16) & 1u)) >> 16);
}
__device__ inline float bf16_lo(uint u) {
    union { uint u; float f; } x; x.u = u << 16; return x.f;
}
__device__ inline float bf16_hi(uint u) {
    union { uint u; float f; } x; x.u = u & 0xFFFF0000u; return x.f;
}

// ===========================================================================
// Single cooperative kernel: phase 0 (weight convert + deg zero) ->
// grid.sync -> phase 1 (scatter ∥ QKV GEMM, interleaved virtual blocks) ->
// grid.sync -> phase 2 (attn + output projection, grid-strided).
// Removes two kernel-boundary drains and the prep dispatch; grid-stride in
// phase 2 additionally smooths degree stragglers.
// ===========================================================================
__global__ __launch_bounds__(256, 4) void fused_all(
    const float* __restrict__ x, const int* __restrict__ ei,
    const float* __restrict__ attn_bias,
    const float* __restrict__ Wq, const float* __restrict__ bq,
    const float* __restrict__ Wk, const float* __restrict__ bk,
    const float* __restrict__ Wv, const float* __restrict__ bv,
    const float* __restrict__ Wo, const float* __restrict__ bo,
    ushort* __restrict__ wb,
    ushort* __restrict__ Qb, ushort* __restrict__ Kb, ushort* __restrict__ Vb,
    int* __restrict__ deg, int2* __restrict__ csr2,
    float* __restrict__ logits, float* __restrict__ out)
{
    __shared__ ushort agg_sh[16 * 136];   // 16 rows x 136 ushorts (272B stride)
    cg::grid_group grid = cg::this_grid();
    const int tid = threadIdx.x;
    const int nb  = gridDim.x;
    const int lane = tid & 63;
    const int wid  = tid >> 6;
    const int ml   = lane & 15;
    const int quad = lane >> 4;

    // ---------------- phase 0: convert 4 weight matrices + zero deg --------
    for (int vb = blockIdx.x; vb < 226; vb += nb) {
        if (vb < 128) {
            int i = vb * 256 + tid;     // pair index, 32768 total
            int j = i * 2;
            const float* src = (j < 16384) ? Wq + j
                             : (j < 32768) ? Wk + (j - 16384)
                             : (j < 49152) ? Wv + (j - 32768)
                             :               Wo + (j - 49152);
            float2 v = *reinterpret_cast<const float2*>(src);
            reinterpret_cast<uint*>(wb)[i] = pack2_bf16(v.x, v.y);
        } else {
            int i = (vb - 128) * 256 + tid;
            if (i < N_NODES) deg[i] = 0;
        }
    }
    grid.sync();

    // ---------------- phase 1: scatter ∥ QKV GEMM (interleaved) ------------
    for (int vb = blockIdx.x; vb < TOT_BLK; vb += nb) {
        if ((vb & 3) == 3) {
            // ---- scatter: 4 edges per thread ----
            int t = (vb >> 2) * 256 + tid;
            int e = t * 4;
            if (e < N_EDGES) {   // N_EDGES % 4 == 0, full int4 always valid
                int4 d = *reinterpret_cast<const int4*>(ei + e);
                int4 s = *reinterpret_cast<const int4*>(ei + N_EDGES + e);
                int p0 = atomicAdd(&deg[d.x], 1);
                if (p0 < MAXDEG) csr2[d.x * MAXDEG + p0] = make_int2(e, s.x);
                int p1 = atomicAdd(&deg[d.y], 1);
                if (p1 < MAXDEG) csr2[d.y * MAXDEG + p1] = make_int2(e + 1, s.y);
                int p2 = atomicAdd(&deg[d.z], 1);
                if (p2 < MAXDEG) csr2[d.z * MAXDEG + p2] = make_int2(e + 2, s.z);
                int p3 = atomicAdd(&deg[d.w], 1);
                if (p3 < MAXDEG) csr2[d.w * MAXDEG + p3] = make_int2(e + 3, s.w);
            }
        } else {
            // ---- GEMM: gi in [0, 3*GBLK) via interleave-inverse mapping ----
            const int gi    = (vb >> 2) * 3 + (vb & 3);
            const int which = gi / GBLK;
            const int mb    = gi - which * GBLK;
            const ushort* W = wb + which * 16384;
            const float* bias = (which == 0) ? bq : (which == 1) ? bk : bv;
            ushort* C = (which == 0) ? Qb : (which == 1) ? Kb : Vb;
            const int m0 = mb * 64 + wid * 16;

            int arow = m0 + ml; if (arow >= N_NODES) arow = N_NODES - 1;
            const float* xp = x + arow * 128 + quad * 8;

            bf16x8 af[4];
#pragma unroll
            for (int ks = 0; ks < 4; ++ks) {
                float4 a0 = *reinterpret_cast<const float4*>(xp + ks * 32);
                float4 a1 = *reinterpret_cast<const float4*>(xp + ks * 32 + 4);
                uint* u = reinterpret_cast<uint*>(&af[ks]);
                u[0] = pack2_bf16(a0.x, a0.y); u[1] = pack2_bf16(a0.z, a0.w);
                u[2] = pack2_bf16(a1.x, a1.y); u[3] = pack2_bf16(a1.z, a1.w);
            }

            f32x4 acc[8];
#pragma unroll
            for (int ct = 0; ct < 8; ++ct) acc[ct] = (f32x4){0.f, 0.f, 0.f, 0.f};

#pragma unroll
            for (int ks = 0; ks < 4; ++ks) {
#pragma unroll
                for (int ct = 0; ct < 8; ++ct) {
                    bf16x8 bf = *reinterpret_cast<const bf16x8*>(
                        W + (ct * 16 + ml) * 128 + ks * 32 + quad * 8);
                    acc[ct] = __builtin_amdgcn_mfma_f32_16x16x32_bf16(af[ks], bf, acc[ct], 0, 0, 0);
                }
            }

#pragma unroll
            for (int ct = 0; ct < 8; ++ct) {
                int col = ct * 16 + ml;
                float b = bias[col];
#pragma unroll
                for (int r = 0; r < 4; ++r) {
                    int row = m0 + quad * 4 + r;
                    if (row < N_NODES)
                        C[row * 128 + col] = cvt_bf16(acc[ct][r] + b);
                }
            }
        }
    }
    grid.sync();

    // ---------------- phase 2: attn + output projection --------------------
    const int h  = lane & 7;
    const int es = lane >> 3;
    const uint4* Qu4 = reinterpret_cast<const uint4*>(Qb);
    const uint4* Ku4 = reinterpret_cast<const uint4*>(Kb);
    const uint4* Vu4 = reinterpret_cast<const uint4*>(Vb);
    const ushort* Wo2 = wb + 3 * 16384;

    // zero rows 4..15 of agg_sh once (they are never written afterwards;
    // first iteration's pre-epilogue __syncthreads publishes them)
    if (tid < 204)
        *reinterpret_cast<uint4*>(reinterpret_cast<char*>(agg_sh) + 1088 + tid * 16) =
            make_uint4(0u, 0u, 0u, 0u);

    for (int vb = blockIdx.x; vb < ATTN_VB; vb += nb) {
        const int n0 = vb * 4;
        const int n  = n0 + wid;
        int dg = deg[n]; if (dg > MAXDEG) dg = MAXDEG;
        const int start = n * MAXDEG;

        // Q[n, h*16 .. +16) -> 16 floats (broadcast across the 8 e_slots)
        uint4 qa = Qu4[n * 16 + h * 2];
        uint4 qb2 = Qu4[n * 16 + h * 2 + 1];
        float qf[16];
        {
            uint qq[8] = {qa.x, qa.y, qa.z, qa.w, qb2.x, qb2.y, qb2.z, qb2.w};
#pragma unroll
            for (int j = 0; j < 8; ++j) {
                qf[2 * j]     = bf16_lo(qq[j]);
                qf[2 * j + 1] = bf16_hi(qq[j]);
            }
        }

        float acc[16];
#pragma unroll
        for (int j = 0; j < 16; ++j) acc[j] = 0.f;
        float z = 0.f;

        if (dg > 0) {
            int2 ep = csr2[start + (es < dg ? es : dg - 1)];
            for (int base = 0; base < dg; base += 8) {
                int e = ep.x, s = ep.y;
                bool valid = (base + es) < dg;

                uint4 k0 = Ku4[s * 16 + h * 2];
                uint4 k1 = Ku4[s * 16 + h * 2 + 1];
                uint4 v0 = Vu4[s * 16 + h * 2];
                uint4 v1 = Vu4[s * 16 + h * 2 + 1];
                float bias = attn_bias[e * 8 + h];

                // prefetch next batch's {e, src} before the VALU work
                int nbatch = base + 8;
                if (nbatch < dg) {
                    int t2 = nbatch + es; if (t2 >= dg) t2 = dg - 1;
                    ep = csr2[start + t2];
                }

                uint kk[8] = {k0.x, k0.y, k0.z, k0.w, k1.x, k1.y, k1.z, k1.w};
                float d = 0.f;
#pragma unroll
                for (int j = 0; j < 8; ++j)
                    d += qf[2 * j] * bf16_lo(kk[j]) + qf[2 * j + 1] * bf16_hi(kk[j]);

                float l = 0.25f * d + bias;
                float p = 0.f;
                if (valid) {
                    __builtin_nontemporal_store(l, &logits[e * 8 + h]);
                    p = __expf(l);
                }
                z += p;

                uint vv[8] = {v0.x, v0.y, v0.z, v0.w, v1.x, v1.y, v1.z, v1.w};
#pragma unroll
                for (int j = 0; j < 8; ++j) {
                    acc[2 * j]     += p * bf16_lo(vv[j]);
                    acc[2 * j + 1] += p * bf16_hi(vv[j]);
                }
            }
        }

        // reduce-scatter butterfly over e_slot bits (lane bits 5,4,3)
        {
            int bit = (lane >> 5) & 1;
#pragma unroll
            for (int j = 0; j < 8; ++j) {
                float send = bit ? acc[j] : acc[j + 8];
                float keep = bit ? acc[j + 8] : acc[j];
                acc[j] = keep + __shfl_xor(send, 32, 64);
            }
            bit = (lane >> 4) & 1;
#pragma unroll
            for (int j = 0; j < 4; ++j) {
                float send = bit ? acc[j] : acc[j + 4];
                float keep = bit ? acc[j + 4] : acc[j];
                acc[j] = keep + __shfl_xor(send, 16, 64);
            }
            bit = (lane >> 3) & 1;
#pragma unroll
            for (int j = 0; j < 2; ++j) {
                float send = bit ? acc[j] : acc[j + 2];
                float keep = bit ? acc[j + 2] : acc[j];
                acc[j] = keep + __shfl_xor(send, 8, 64);
            }
        }
        z += __shfl_xor(z, 8, 64);
        z += __shfl_xor(z, 16, 64);
        z += __shfl_xor(z, 32, 64);

        float inv = (z > 0.f) ? 1.f / z : 0.f;
        int d_off = ((lane >> 5) & 1) * 8 + ((lane >> 4) & 1) * 4 + ((lane >> 3) & 1) * 2;
        *reinterpret_cast<uint*>(reinterpret_cast<char*>(agg_sh) + wid * 272 +
                                 (h * 16 + d_off) * 2) =
            pack2_bf16(acc[0] * inv, acc[1] * inv);

        __syncthreads();

        // ---- all 4 waves: output projection, 2 column-tiles each ----
        {
            bf16x8 af[4];
#pragma unroll
            for (int ks = 0; ks < 4; ++ks)
                af[ks] = *reinterpret_cast<const bf16x8*>(
                    reinterpret_cast<char*>(agg_sh) + ml * 272 + ks * 64 + quad * 16);

            f32x4 oacc[2];
            oacc[0] = (f32x4){0.f, 0.f, 0.f, 0.f};
            oacc[1] = (f32x4){0.f, 0.f, 0.f, 0.f};

#pragma unroll
            for (int ks = 0; ks < 4; ++ks) {
#pragma unroll
                for (int c = 0; c < 2; ++c) {
                    bf16x8 bf = *reinterpret_cast<const bf16x8*>(
                        Wo2 + ((wid * 2 + c) * 16 + ml) * 128 + ks * 32 + quad * 8);
                    oacc[c] = __builtin_amdgcn_mfma_f32_16x16x32_bf16(af[ks], bf, oacc[c], 0, 0, 0);
                }
            }

            if (quad == 0) {   // rows 0..3 = this group's 4 nodes
#pragma unroll
                for (int c = 0; c < 2; ++c) {
                    int col = (wid * 2 + c) * 16 + ml;
                    float b = bo[col];
#pragma unroll
                    for (int r = 0; r < 4; ++r)
                        out[(n0 + r) * 128 + col] = oacc[c][r] + b;
                }
            }
        }
        __syncthreads();   // protect agg_sh rows 0..3 before next vb writes
    }
}

// ===========================================================================
// Fallback path (identical to R8's three kernels) in case cooperative launch
// is unavailable under graph capture.
// ===========================================================================
__global__ __launch_bounds__(256) void prep(
    const float* __restrict__ Wq, const float* __restrict__ Wk,
    const float* __restrict__ Wv, const float* __restrict__ Wo,
    ushort* __restrict__ wb, int* __restrict__ deg)
{
    int i = blockIdx.x * 256 + threadIdx.x;
    if (i < N_NODES) deg[i] = 0;
    if (i < 32768) {
        int j = i * 2;
        const float* src = (j < 16384) ? Wq + j
                         : (j < 32768) ? Wk + (j - 16384)
                         : (j < 49152) ? Wv + (j - 32768)
                         :               Wo + (j - 49152);
        float2 v = *reinterpret_cast<const float2*>(src);
        reinterpret_cast<uint*>(wb)[i] = pack2_bf16(v.x, v.y);
    }
}

__global__ __launch_bounds__(256) void gemm_qkv_scatter(
    const float* __restrict__ x, const ushort* __restrict__ Wall,
    const float* __restrict__ bq, const float* __restrict__ bk,
    const float* __restrict__ bv,
    ushort* __restrict__ Qb, ushort* __restrict__ Kb, ushort* __restrict__ Vb,
    const int* __restrict__ ei, int* __restrict__ deg, int2* __restrict__ csr2)
{
    const int bx = blockIdx.x;
    if ((bx & 3) == 3) {
        int t = (bx >> 2) * 256 + threadIdx.x;
        int e = t * 4;
        if (e < N_EDGES) {
            int4 d = *reinterpret_cast<const int4*>(ei + e);
            int4 s = *reinterpret_cast<const int4*>(ei + N_EDGES + e);
            int p0 = atomicAdd(&deg[d.x], 1);
            if (p0 < MAXDEG) csr2[d.x * MAXDEG + p0] = make_int2(e, s.x);
            int p1 = atomicAdd(&deg[d.y], 1);
            if (p1 < MAXDEG) csr2[d.y * MAXDEG + p1] = make_int2(e + 1, s.y);
            int p2 = atomicAdd(&deg[d.z], 1);
            if (p2 < MAXDEG) csr2[d.z * MAXDEG + p2] = make_int2(e + 2, s.z);
            int p3 = atomicAdd(&deg[d.w], 1);
            if (p3 < MAXDEG) csr2[d.w * MAXDEG + p3] = make_int2(e + 3, s.w);
        }
        return;
    }
    const int gi    = (bx >> 2) * 3 + (bx & 3);
    const int which = gi / GBLK;
    const int mb    = gi - which * GBLK;
    const ushort* W = Wall + which * 16384;
    const float* bias = (which == 0) ? bq : (which == 1) ? bk : bv;
    ushort* C = (which == 0) ? Qb : (which == 1) ? Kb : Vb;

    const int lane = threadIdx.x & 63;
    const int wave = threadIdx.x >> 6;
    const int ml   = lane & 15;
    const int quad = lane >> 4;
    const int m0   = mb * 64 + wave * 16;

    int arow = m0 + ml; if (arow >= N_NODES) arow = N_NODES - 1;
    const float* xp = x + arow * 128 + quad * 8;

    bf16x8 af[4];
#pragma unroll
    for (int ks = 0; ks < 4; ++ks) {
        float4 a0 = *reinterpret_cast<const float4*>(xp + ks * 32);
        float4 a1 = *reinterpret_cast<const float4*>(xp + ks * 32 + 4);
        uint* u = reinterpret_cast<uint*>(&af[ks]);
        u[0] = pack2_bf16(a0.x, a0.y); u[1] = pack2_bf16(a0.z, a0.w);
        u[2] = pack2_bf16(a1.x, a1.y); u[3] = pack2_bf16(a1.z, a1.w);
    }

    f32x4 acc[8];
#pragma unroll
    for (int ct = 0; ct < 8; ++ct) acc[ct] = (f32x4){0.f, 0.f, 0.f, 0.f};

#pragma unroll
    for (int ks = 0; ks < 4; ++ks) {
#pragma unroll
        for (int ct = 0; ct < 8; ++ct) {
            bf16x8 bf = *reinterpret_cast<const bf16x8*>(
                W + (ct * 16 + ml) * 128 + ks * 32 + quad * 8);
            acc[ct] = __builtin_amdgcn_mfma_f32_16x16x32_bf16(af[ks], bf, acc[ct], 0, 0, 0);
        }
    }

#pragma unroll
    for (int ct = 0; ct < 8; ++ct) {
        int col = ct * 16 + ml;
        float b = bias[col];
#pragma unroll
        for (int r = 0; r < 4; ++r) {
            int row = m0 + quad * 4 + r;
            if (row < N_NODES)
                C[row * 128 + col] = cvt_bf16(acc[ct][r] + b);
        }
    }
}

__global__ __launch_bounds__(256) void fused_attn_out(
    const ushort* __restrict__ Q2, const ushort* __restrict__ K2,
    const ushort* __restrict__ V2,
    const float* __restrict__ attn_bias,
    const int* __restrict__ deg, const int2* __restrict__ csr2,
    const ushort* __restrict__ Wo2, const float* __restrict__ bo,
    float* __restrict__ logits, float* __restrict__ out)
{
    __shared__ ushort agg_sh[16 * 136];

    const int tid  = threadIdx.x;
    const int lane = tid & 63;
    const int wid  = tid >> 6;
    const int n0 = blockIdx.x * 4;
    const int n  = n0 + wid;
    int dg = deg[n]; if (dg > MAXDEG) dg = MAXDEG;
    const int start = n * MAXDEG;
    const int h  = lane & 7;
    const int es = lane >> 3;
    const int ml   = lane & 15;
    const int quad = lane >> 4;

    if (tid < 204)
        *reinterpret_cast<uint4*>(reinterpret_cast<char*>(agg_sh) + 1088 + tid * 16) =
            make_uint4(0u, 0u, 0u, 0u);

    const uint4* Qu4 = reinterpret_cast<const uint4*>(Q2);
    const uint4* Ku4 = reinterpret_cast<const uint4*>(K2);
    const uint4* Vu4 = reinterpret_cast<const uint4*>(V2);

    uint4 qa = Qu4[n * 16 + h * 2];
    uint4 qb = Qu4[n * 16 + h * 2 + 1];
    float qf[16];
    {
        uint qq[8] = {qa.x, qa.y, qa.z, qa.w, qb.x, qb.y, qb.z, qb.w};
#pragma unroll
        for (int j = 0; j < 8; ++j) {
            qf[2 * j]     = bf16_lo(qq[j]);
            qf[2 * j + 1] = bf16_hi(qq[j]);
        }
    }

    float acc[16];
#pragma unroll
    for (int j = 0; j < 16; ++j) acc[j] = 0.f;
    float z = 0.f;

    if (dg > 0) {
        int2 ep = csr2[start + (es < dg ? es : dg - 1)];
        for (int base = 0; base < dg; base += 8) {
            int e = ep.x, s = ep.y;
            bool valid = (base + es) < dg;

            uint4 k0 = Ku4[s * 16 + h * 2];
            uint4 k1 = Ku4[s * 16 + h * 2 + 1];
            uint4 v0 = Vu4[s * 16 + h * 2];
            uint4 v1 = Vu4[s * 16 + h * 2 + 1];
            float bias = attn_bias[e * 8 + h];

            int nb = base + 8;
            if (nb < dg) {
                int t2 = nb + es; if (t2 >= dg) t2 = dg - 1;
                ep = csr2[start + t2];
            }

            uint kk[8] = {k0.x, k0.y, k0.z, k0.w, k1.x, k1.y, k1.z, k1.w};
            float d = 0.f;
#pragma unroll
            for (int j = 0; j < 8; ++j)
                d += qf[2 * j] * bf16_lo(kk[j]) + qf[2 * j + 1] * bf16_hi(kk[j]);

            float l = 0.25f * d + bias;
            float p = 0.f;
            if (valid) {
                __builtin_nontemporal_store(l, &logits[e * 8 + h]);
                p = __expf(l);
            }
            z += p;

            uint vv[8] = {v0.x, v0.y, v0.z, v0.w, v1.x, v1.y, v1.z, v1.w};
#pragma unroll
            for (int j = 0; j < 8; ++j) {
                acc[2 * j]     += p * bf16_lo(vv[j]);
                acc[2 * j + 1] += p * bf16_hi(vv[j]);
            }
        }
    }

    {
        int bit = (lane >> 5) & 1;
#pragma unroll
        for (int j = 0; j < 8; ++j) {
            float send = bit ? acc[j] : acc[j + 8];
            float keep = bit ? acc[j + 8] : acc[j];
            acc[j] = keep + __shfl_xor(send, 32, 64);
        }
        bit = (lane >> 4) & 1;
#pragma unroll
        for (int j = 0; j < 4; ++j) {
            float send = bit ? acc[j] : acc[j + 4];
            float keep = bit ? acc[j + 4] : acc[j];
            acc[j] = keep + __shfl_xor(send, 16, 64);
        }
        bit = (lane >> 3) & 1;
#pragma unroll
        for (int j = 0; j < 2; ++j) {
            float send = bit ? acc[j] : acc[j + 2];
            float keep = bit ? acc[j + 2] : acc[j];
            acc[j] = keep + __shfl_xor(send, 8, 64);
        }
    }
    z += __shfl_xor(z, 8, 64);
    z += __shfl_xor(z, 16, 64);
    z += __shfl_xor(z, 32, 64);

    float inv = (z > 0.f) ? 1.f / z : 0.f;
    int d_off = ((lane >> 5) & 1) * 8 + ((lane >> 4) & 1) * 4 + ((lane >> 3) & 1) * 2;
    *reinterpret_cast<uint*>(reinterpret_cast<char*>(agg_sh) + wid * 272 +
                             (h * 16 + d_off) * 2) =
        pack2_bf16(acc[0] * inv, acc[1] * inv);

    __syncthreads();

    {
        bf16x8 af[4];
#pragma unroll
        for (int ks = 0; ks < 4; ++ks)
            af[ks] = *reinterpret_cast<const bf16x8*>(
                reinterpret_cast<char*>(agg_sh) + ml * 272 + ks * 64 + quad * 16);

        f32x4 oacc[2];
        oacc[0] = (f32x4){0.f, 0.f, 0.f, 0.f};
        oacc[1] = (f32x4){0.f, 0.f, 0.f, 0.f};

#pragma unroll
        for (int ks = 0; ks < 4; ++ks) {
#pragma unroll
            for (int c = 0; c < 2; ++c) {
                bf16x8 bf = *reinterpret_cast<const bf16x8*>(
                    Wo2 + ((wid * 2 + c) * 16 + ml) * 128 + ks * 32 + quad * 8);
                oacc[c] = __builtin_amdgcn_mfma_f32_16x16x32_bf16(af[ks], bf, oacc[c], 0, 0, 0);
            }
        }

        if (quad == 0) {
#pragma unroll
            for (int c = 0; c < 2; ++c) {
                int col = (wid * 2 + c) * 16 + ml;
                float b = bo[col];
#pragma unroll
                for (int r = 0; r < 4; ++r)
                    out[(n0 + r) * 128 + col] = oacc[c][r] + b;
            }
        }
    }
}

// ---------------------------------------------------------------------------
extern "C" void kernel_launch(void* const* d_in, const int* in_sizes, int n_in,
                              void* d_out, int out_size, void* d_ws, size_t ws_size,
                              hipStream_t stream)
{
    const float* x         = (const float*)d_in[0];
    const int*   ei        = (const int*)  d_in[1];
    const float* attn_bias = (const float*)d_in[2];
    const float* Wq = (const float*)d_in[3];
    const float* bq = (const float*)d_in[4];
    const float* Wk = (const float*)d_in[5];
    const float* bk = (const float*)d_in[6];
    const float* Wv = (const float*)d_in[7];
    const float* bv = (const float*)d_in[8];
    const float* Wo = (const float*)d_in[9];
    const float* bo = (const float*)d_in[10];

    float* out    = (float*)d_out;                // [N,128]
    float* logits = out + N_NODES * EMBED;        // [E,8] (output 1)

    ushort* wb   = (ushort*)d_ws;                 // 4*16384 (Wq,Wk,Wv,Wo)
    ushort* Qb   = wb + 4 * 16384;                // N*128
    ushort* Kb   = Qb + NX;                       // N*128
    ushort* Vb   = Kb + NX;                       // N*128
    int* deg     = (int*)(Vb + NX);               // N (doubles as append cursor)
    int2* csr2   = (int2*)(deg + N_NODES);        // N*MAXDEG pairs {edge, src}

    // grid sizing for cooperative launch: blocks/CU from the occupancy API,
    // clamped; MI355X has 256 CUs. Grid-stride loops handle any grid size.
    int per_cu = 4;
    if (hipOccupancyMaxActiveBlocksPerMultiprocessor(
            &per_cu, reinterpret_cast<const void*>(fused_all), 256, 0) != hipSuccess
        || per_cu < 1)
        per_cu = 4;
    if (per_cu > 8) per_cu = 8;
    int grid = per_cu * 256;
    if (grid > 2048) grid = 2048;

    void* kargs[] = {
        (void*)&x, (void*)&ei, (void*)&attn_bias,
        (void*)&Wq, (void*)&bq, (void*)&Wk, (void*)&bk,
        (void*)&Wv, (void*)&bv, (void*)&Wo, (void*)&bo,
        (void*)&wb, (void*)&Qb, (void*)&Kb, (void*)&Vb,
        (void*)&deg, (void*)&csr2, (void*)&logits, (void*)&out
    };

    hipError_t err = hipLaunchCooperativeKernel(
        reinterpret_cast<const void*>(fused_all),
        dim3(grid), dim3(256), kargs, 0, stream);

    if (err != hipSuccess) {
        // Fallback: proven 3-kernel path (R8)
        prep<<<128, 256, 0, stream>>>(Wq, Wk, Wv, Wo, wb, deg);
        gemm_qkv_scatter<<<TOT_BLK, 256, 0, stream>>>(
            x, wb, bq, bk, bv, Qb, Kb, Vb, ei, deg, csr2);
        fused_attn_out<<<N_NODES / 4, 256, 0, stream>>>(Qb, Kb, Vb, attn_bias,
                                                        deg, csr2, wb + 3 * 16384,
                                                        bo, logits, out);
    }
}

// Round 10
// 248.894 us; speedup vs baseline: 1.2745x; 1.2745x over previous
//
#include <hip/hip_runtime.h>
#include <math.h>

#define N_NODES 25000
#define N_EDGES 400000
#define EMBED   128
#define HEADS   8
#define DK      16
#define MAXDEG  96        // Poisson(16) max over 25000 nodes ~ 45; 96 is ultra-safe
#define NX (N_NODES * 128)
#define GBLK 391                         // ceil(25000/64) GEMM row-blocks
#define SCAT_BLK 391                     // ceil(400000/(256*4)) scatter blocks
#define TOT_BLK (3 * GBLK + SCAT_BLK)    // 1564

typedef __attribute__((ext_vector_type(8))) short bf16x8;
typedef __attribute__((ext_vector_type(4))) float f32x4;
typedef unsigned int uint;
typedef unsigned short ushort;

__device__ inline uint pack2_bf16(float a, float b) {
    union { float f; uint u; } ua, ub;
    ua.f = a; ub.f = b;
    uint ra = (ua.u + 0x7FFFu + ((ua.u >> 16) & 1u)) >> 16;
    uint rb = (ub.u + 0x7FFFu + ((ub.u >> 16) & 1u)) >> 16;
    return (ra & 0xFFFFu) | (rb << 16);
}
__device__ inline ushort cvt_bf16(float a) {
    union { float f; uint u; } ua; ua.f = a;
    return (ushort)((ua.u + 0x7FFFu + ((ua.u >> 16) & 1u)) >> 16);
}
__device__ inline float bf16_lo(uint u) {
    union { uint u; float f; } x; x.u = u << 16; return x.f;
}
__device__ inline float bf16_hi(uint u) {
    union { uint u; float f; } x; x.u = u & 0xFFFF0000u; return x.f;
}

// ---------------------------------------------------------------------------
// prep: convert the four 128x128 weights to bf16 (2 floats/thread) and zero
// the degree counters.
// ---------------------------------------------------------------------------
__global__ __launch_bounds__(256) void prep(
    const float* __restrict__ Wq, const float* __restrict__ Wk,
    const float* __restrict__ Wv, const float* __restrict__ Wo,
    ushort* __restrict__ wb, int* __restrict__ deg)
{
    int i = blockIdx.x * 256 + threadIdx.x;
    if (i < N_NODES) deg[i] = 0;
    if (i < 32768) {
        int j = i * 2;
        const float* src = (j < 16384) ? Wq + j
                         : (j < 32768) ? Wk + (j - 16384)
                         : (j < 49152) ? Wv + (j - 32768)
                         :               Wo + (j - 49152);
        float2 v = *reinterpret_cast<const float2*>(src);
        reinterpret_cast<uint*>(wb)[i] = pack2_bf16(v.x, v.y);
    }
}

// ---------------------------------------------------------------------------
// Merged Q/K/V GEMM + padded-CSR scatter, INTERLEAVED block types (R8):
// bx%4==3 -> scatter (391 of 1564 blocks), else GEMM (1173 blocks), so both
// block types share every CU and the scatter's atomic/store latency hides
// under GEMM MFMA work.
// ---------------------------------------------------------------------------
__global__ __launch_bounds__(256) void gemm_qkv_scatter(
    const float* __restrict__ x, const ushort* __restrict__ Wall,
    const float* __restrict__ bq, const float* __restrict__ bk,
    const float* __restrict__ bv,
    ushort* __restrict__ Qb, ushort* __restrict__ Kb, ushort* __restrict__ Vb,
    const int* __restrict__ ei, int* __restrict__ deg, int2* __restrict__ csr2)
{
    const int bx = blockIdx.x;
    if ((bx & 3) == 3) {
        // ---- scatter: 4 edges per thread ----
        int t = (bx >> 2) * 256 + threadIdx.x;
        int e = t * 4;
        if (e < N_EDGES) {   // N_EDGES % 4 == 0, full int4 always valid
            int4 d = *reinterpret_cast<const int4*>(ei + e);
            int4 s = *reinterpret_cast<const int4*>(ei + N_EDGES + e);
            int p0 = atomicAdd(&deg[d.x], 1);
            if (p0 < MAXDEG) csr2[d.x * MAXDEG + p0] = make_int2(e, s.x);
            int p1 = atomicAdd(&deg[d.y], 1);
            if (p1 < MAXDEG) csr2[d.y * MAXDEG + p1] = make_int2(e + 1, s.y);
            int p2 = atomicAdd(&deg[d.z], 1);
            if (p2 < MAXDEG) csr2[d.z * MAXDEG + p2] = make_int2(e + 2, s.z);
            int p3 = atomicAdd(&deg[d.w], 1);
            if (p3 < MAXDEG) csr2[d.w * MAXDEG + p3] = make_int2(e + 3, s.w);
        }
        return;
    }

    // ---- GEMM: gi in [0, 3*GBLK) via interleave-inverse mapping ----
    const int gi    = (bx >> 2) * 3 + (bx & 3);
    const int which = gi / GBLK;
    const int mb    = gi - which * GBLK;
    const ushort* W = Wall + which * 16384;
    const float* bias = (which == 0) ? bq : (which == 1) ? bk : bv;
    ushort* C = (which == 0) ? Qb : (which == 1) ? Kb : Vb;

    const int lane = threadIdx.x & 63;
    const int wave = threadIdx.x >> 6;
    const int ml   = lane & 15;
    const int quad = lane >> 4;
    const int m0   = mb * 64 + wave * 16;

    int arow = m0 + ml; if (arow >= N_NODES) arow = N_NODES - 1;
    const float* xp = x + arow * 128 + quad * 8;

    // A fragments for all 4 K-steps, converted once
    bf16x8 af[4];
#pragma unroll
    for (int ks = 0; ks < 4; ++ks) {
        float4 a0 = *reinterpret_cast<const float4*>(xp + ks * 32);
        float4 a1 = *reinterpret_cast<const float4*>(xp + ks * 32 + 4);
        uint* u = reinterpret_cast<uint*>(&af[ks]);
        u[0] = pack2_bf16(a0.x, a0.y); u[1] = pack2_bf16(a0.z, a0.w);
        u[2] = pack2_bf16(a1.x, a1.y); u[3] = pack2_bf16(a1.z, a1.w);
    }

    f32x4 acc[8];
#pragma unroll
    for (int ct = 0; ct < 8; ++ct) acc[ct] = (f32x4){0.f, 0.f, 0.f, 0.f};

#pragma unroll
    for (int ks = 0; ks < 4; ++ks) {
#pragma unroll
        for (int ct = 0; ct < 8; ++ct) {
            bf16x8 bf = *reinterpret_cast<const bf16x8*>(
                W + (ct * 16 + ml) * 128 + ks * 32 + quad * 8);
            acc[ct] = __builtin_amdgcn_mfma_f32_16x16x32_bf16(af[ks], bf, acc[ct], 0, 0, 0);
        }
    }

#pragma unroll
    for (int ct = 0; ct < 8; ++ct) {
        int col = ct * 16 + ml;
        float b = bias[col];
#pragma unroll
        for (int r = 0; r < 4; ++r) {
            int row = m0 + quad * 4 + r;
            if (row < N_NODES)
                C[row * 128 + col] = cvt_bf16(acc[ct][r] + b);
        }
    }
}

// ---------------------------------------------------------------------------
// Fused attention + output projection with FULLY INDEPENDENT WAVES.
// 4 nodes/block, one per wave, but NO __syncthreads and no shared agg tile:
// each wave writes its 256B agg row into its own LDS slice (same-wave
// visibility needs no barrier) and runs its own 8x4-MFMA projection against
// Wo. Key trick: only C-row 0 of each 16x16 MFMA is consumed, and C-row 0
// depends only on A-row 0 — so A rows 1..15 can hold garbage (no zero-fill,
// no dense-tile packing). Removes the max-of-4-degrees straggler coupling
// (~+50% on the gather phase) that the barrier imposed in R4/R8.
// ---------------------------------------------------------------------------
__global__ __launch_bounds__(256) void fused_attn_out(
    const ushort* __restrict__ Q2, const ushort* __restrict__ K2,
    const ushort* __restrict__ V2,
    const float* __restrict__ attn_bias,
    const int* __restrict__ deg, const int2* __restrict__ csr2,
    const ushort* __restrict__ Wo2, const float* __restrict__ bo,
    float* __restrict__ logits, float* __restrict__ out)
{
    __shared__ ushort agg_sh[4 * 128];    // 256B per wave, private slices

    const int tid  = threadIdx.x;
    const int lane = tid & 63;
    const int wid  = tid >> 6;
    const int n = blockIdx.x * 4 + wid;
    int dg = deg[n]; if (dg > MAXDEG) dg = MAXDEG;
    const int start = n * MAXDEG;
    const int h  = lane & 7;
    const int es = lane >> 3;
    const int ml   = lane & 15;
    const int quad = lane >> 4;

    const uint4* Qu4 = reinterpret_cast<const uint4*>(Q2);
    const uint4* Ku4 = reinterpret_cast<const uint4*>(K2);
    const uint4* Vu4 = reinterpret_cast<const uint4*>(V2);

    // Q[n, h*16 .. +16) -> 16 floats (broadcast across the 8 e_slots)
    uint4 qa = Qu4[n * 16 + h * 2];
    uint4 qb = Qu4[n * 16 + h * 2 + 1];
    float qf[16];
    {
        uint qq[8] = {qa.x, qa.y, qa.z, qa.w, qb.x, qb.y, qb.z, qb.w};
#pragma unroll
        for (int j = 0; j < 8; ++j) {
            qf[2 * j]     = bf16_lo(qq[j]);
            qf[2 * j + 1] = bf16_hi(qq[j]);
        }
    }

    float acc[16];
#pragma unroll
    for (int j = 0; j < 16; ++j) acc[j] = 0.f;
    float z = 0.f;

    if (dg > 0) {
        int2 ep = csr2[start + (es < dg ? es : dg - 1)];
        for (int base = 0; base < dg; base += 8) {
            int e = ep.x, s = ep.y;
            bool valid = (base + es) < dg;

            uint4 k0 = Ku4[s * 16 + h * 2];
            uint4 k1 = Ku4[s * 16 + h * 2 + 1];
            uint4 v0 = Vu4[s * 16 + h * 2];
            uint4 v1 = Vu4[s * 16 + h * 2 + 1];
            float bias = attn_bias[e * 8 + h];

            // prefetch next batch's {e, src} before the VALU work
            int nb = base + 8;
            if (nb < dg) {
                int t2 = nb + es; if (t2 >= dg) t2 = dg - 1;
                ep = csr2[start + t2];
            }

            uint kk[8] = {k0.x, k0.y, k0.z, k0.w, k1.x, k1.y, k1.z, k1.w};
            float d = 0.f;
#pragma unroll
            for (int j = 0; j < 8; ++j)
                d += qf[2 * j] * bf16_lo(kk[j]) + qf[2 * j + 1] * bf16_hi(kk[j]);

            float l = 0.25f * d + bias;
            float p = 0.f;
            if (valid) {
                __builtin_nontemporal_store(l, &logits[e * 8 + h]);
                p = __expf(l);
            }
            z += p;

            uint vv[8] = {v0.x, v0.y, v0.z, v0.w, v1.x, v1.y, v1.z, v1.w};
#pragma unroll
            for (int j = 0; j < 8; ++j) {
                acc[2 * j]     += p * bf16_lo(vv[j]);
                acc[2 * j + 1] += p * bf16_hi(vv[j]);
            }
        }
    }

    // reduce-scatter butterfly over e_slot bits (lane bits 5,4,3)
    {
        int bit = (lane >> 5) & 1;
#pragma unroll
        for (int j = 0; j < 8; ++j) {
            float send = bit ? acc[j] : acc[j + 8];
            float keep = bit ? acc[j + 8] : acc[j];
            acc[j] = keep + __shfl_xor(send, 32, 64);
        }
        bit = (lane >> 4) & 1;
#pragma unroll
        for (int j = 0; j < 4; ++j) {
            float send = bit ? acc[j] : acc[j + 4];
            float keep = bit ? acc[j + 4] : acc[j];
            acc[j] = keep + __shfl_xor(send, 16, 64);
        }
        bit = (lane >> 3) & 1;
#pragma unroll
        for (int j = 0; j < 2; ++j) {
            float send = bit ? acc[j] : acc[j + 2];
            float keep = bit ? acc[j + 2] : acc[j];
            acc[j] = keep + __shfl_xor(send, 8, 64);
        }
    }
    z += __shfl_xor(z, 8, 64);
    z += __shfl_xor(z, 16, 64);
    z += __shfl_xor(z, 32, 64);

    float inv = (z > 0.f) ? 1.f / z : 0.f;
    // lane holds output dims h*16 + d_off + {0,1}; write bf16 pair to this
    // wave's private LDS slice (same-wave read below -> no barrier needed)
    char* wbase = reinterpret_cast<char*>(agg_sh) + wid * 256;
    int d_off = ((lane >> 5) & 1) * 8 + ((lane >> 4) & 1) * 4 + ((lane >> 3) & 1) * 2;
    *reinterpret_cast<uint*>(wbase + (h * 16 + d_off) * 2) =
        pack2_bf16(acc[0] * inv, acc[1] * inv);

    // ---- per-wave output projection: A-row 0 = this node's agg; rows 1..15
    //      read duplicate/garbage data and are discarded (only C-row 0 used)
    {
        bf16x8 af[4];
#pragma unroll
        for (int ks = 0; ks < 4; ++ks)
            af[ks] = *reinterpret_cast<const bf16x8*>(wbase + ks * 64 + quad * 16);

#pragma unroll
        for (int ct = 0; ct < 8; ++ct) {
            f32x4 o = (f32x4){0.f, 0.f, 0.f, 0.f};
#pragma unroll
            for (int ks = 0; ks < 4; ++ks) {
                bf16x8 bf = *reinterpret_cast<const bf16x8*>(
                    Wo2 + (ct * 16 + ml) * 128 + ks * 32 + quad * 8);
                o = __builtin_amdgcn_mfma_f32_16x16x32_bf16(af[ks], bf, o, 0, 0, 0);
            }
            if (quad == 0) {   // C-row 0 = the node
                int col = ct * 16 + ml;
                out[n * 128 + col] = o[0] + bo[col];
            }
        }
    }
}

// ---------------------------------------------------------------------------
extern "C" void kernel_launch(void* const* d_in, const int* in_sizes, int n_in,
                              void* d_out, int out_size, void* d_ws, size_t ws_size,
                              hipStream_t stream)
{
    const float* x         = (const float*)d_in[0];
    const int*   ei        = (const int*)  d_in[1];
    const float* attn_bias = (const float*)d_in[2];
    const float* Wq = (const float*)d_in[3];
    const float* bq = (const float*)d_in[4];
    const float* Wk = (const float*)d_in[5];
    const float* bk = (const float*)d_in[6];
    const float* Wv = (const float*)d_in[7];
    const float* bv = (const float*)d_in[8];
    const float* Wo = (const float*)d_in[9];
    const float* bo = (const float*)d_in[10];

    float* out    = (float*)d_out;                // [N,128]
    float* logits = out + N_NODES * EMBED;        // [E,8] (output 1)

    ushort* wb   = (ushort*)d_ws;                 // 4*16384 (Wq,Wk,Wv,Wo)
    ushort* Qb   = wb + 4 * 16384;                // N*128
    ushort* Kb   = Qb + NX;                       // N*128
    ushort* Vb   = Kb + NX;                       // N*128
    int* deg     = (int*)(Vb + NX);               // N (doubles as append cursor)
    int2* csr2   = (int2*)(deg + N_NODES);        // N*MAXDEG pairs {edge, src}

    prep<<<128, 256, 0, stream>>>(Wq, Wk, Wv, Wo, wb, deg);

    gemm_qkv_scatter<<<TOT_BLK, 256, 0, stream>>>(
        x, wb, bq, bk, bv, Qb, Kb, Vb, ei, deg, csr2);

    fused_attn_out<<<N_NODES / 4, 256, 0, stream>>>(Qb, Kb, Vb, attn_bias,
                                                    deg, csr2, wb + 3 * 16384,
                                                    bo, logits, out);
}

// Round 11
// 187.079 us; speedup vs baseline: 1.6957x; 1.3304x over previous
//
#include <hip/hip_runtime.h>
#include <math.h>

#define N_NODES 25000
#define N_EDGES 400000
#define EMBED   128
#define HEADS   8
#define DK      16
#define MAXDEG  96        // Poisson(16) max over 25000 nodes ~ 45; 96 is ultra-safe
#define NX (N_NODES * 128)
#define GBLK 391                         // ceil(25000/64) GEMM row-blocks
#define SCAT_BLK 391                     // ceil(400000/(256*4)) scatter blocks
#define TOT_BLK (3 * GBLK + SCAT_BLK)    // 1564

typedef __attribute__((ext_vector_type(8))) short bf16x8;
typedef __attribute__((ext_vector_type(4))) float f32x4;
typedef unsigned int uint;
typedef unsigned short ushort;

__device__ inline uint pack2_bf16(float a, float b) {
    union { float f; uint u; } ua, ub;
    ua.f = a; ub.f = b;
    uint ra = (ua.u + 0x7FFFu + ((ua.u >> 16) & 1u)) >> 16;
    uint rb = (ub.u + 0x7FFFu + ((ub.u >> 16) & 1u)) >> 16;
    return (ra & 0xFFFFu) | (rb << 16);
}
__device__ inline ushort cvt_bf16(float a) {
    union { float f; uint u; } ua; ua.f = a;
    return (ushort)((ua.u + 0x7FFFu + ((ua.u >> 16) & 1u)) >> 16);
}
__device__ inline float bf16_lo(uint u) {
    union { uint u; float f; } x; x.u = u << 16; return x.f;
}
__device__ inline float bf16_hi(uint u) {
    union { uint u; float f; } x; x.u = u & 0xFFFF0000u; return x.f;
}

// ---------------------------------------------------------------------------
// prep: convert the four 128x128 weights to bf16 (2 floats/thread) and zero
// the degree counters.
// ---------------------------------------------------------------------------
__global__ __launch_bounds__(256) void prep(
    const float* __restrict__ Wq, const float* __restrict__ Wk,
    const float* __restrict__ Wv, const float* __restrict__ Wo,
    ushort* __restrict__ wb, int* __restrict__ deg)
{
    int i = blockIdx.x * 256 + threadIdx.x;
    if (i < N_NODES) deg[i] = 0;
    if (i < 32768) {
        int j = i * 2;
        const float* src = (j < 16384) ? Wq + j
                         : (j < 32768) ? Wk + (j - 16384)
                         : (j < 49152) ? Wv + (j - 32768)
                         :               Wo + (j - 49152);
        float2 v = *reinterpret_cast<const float2*>(src);
        reinterpret_cast<uint*>(wb)[i] = pack2_bf16(v.x, v.y);
    }
}

// ---------------------------------------------------------------------------
// Merged Q/K/V GEMM + padded-CSR scatter, INTERLEAVED block types (R8):
// bx%4==3 -> scatter (391 of 1564 blocks), else GEMM (1173 blocks), so both
// block types share every CU and the scatter's atomic/store latency hides
// under GEMM MFMA work.
// ---------------------------------------------------------------------------
__global__ __launch_bounds__(256) void gemm_qkv_scatter(
    const float* __restrict__ x, const ushort* __restrict__ Wall,
    const float* __restrict__ bq, const float* __restrict__ bk,
    const float* __restrict__ bv,
    ushort* __restrict__ Qb, ushort* __restrict__ Kb, ushort* __restrict__ Vb,
    const int* __restrict__ ei, int* __restrict__ deg, int2* __restrict__ csr2)
{
    const int bx = blockIdx.x;
    if ((bx & 3) == 3) {
        // ---- scatter: 4 edges per thread ----
        int t = (bx >> 2) * 256 + threadIdx.x;
        int e = t * 4;
        if (e < N_EDGES) {   // N_EDGES % 4 == 0, full int4 always valid
            int4 d = *reinterpret_cast<const int4*>(ei + e);
            int4 s = *reinterpret_cast<const int4*>(ei + N_EDGES + e);
            int p0 = atomicAdd(&deg[d.x], 1);
            if (p0 < MAXDEG) csr2[d.x * MAXDEG + p0] = make_int2(e, s.x);
            int p1 = atomicAdd(&deg[d.y], 1);
            if (p1 < MAXDEG) csr2[d.y * MAXDEG + p1] = make_int2(e + 1, s.y);
            int p2 = atomicAdd(&deg[d.z], 1);
            if (p2 < MAXDEG) csr2[d.z * MAXDEG + p2] = make_int2(e + 2, s.z);
            int p3 = atomicAdd(&deg[d.w], 1);
            if (p3 < MAXDEG) csr2[d.w * MAXDEG + p3] = make_int2(e + 3, s.w);
        }
        return;
    }

    // ---- GEMM: gi in [0, 3*GBLK) via interleave-inverse mapping ----
    const int gi    = (bx >> 2) * 3 + (bx & 3);
    const int which = gi / GBLK;
    const int mb    = gi - which * GBLK;
    const ushort* W = Wall + which * 16384;
    const float* bias = (which == 0) ? bq : (which == 1) ? bk : bv;
    ushort* C = (which == 0) ? Qb : (which == 1) ? Kb : Vb;

    const int lane = threadIdx.x & 63;
    const int wave = threadIdx.x >> 6;
    const int ml   = lane & 15;
    const int quad = lane >> 4;
    const int m0   = mb * 64 + wave * 16;

    int arow = m0 + ml; if (arow >= N_NODES) arow = N_NODES - 1;
    const float* xp = x + arow * 128 + quad * 8;

    // A fragments for all 4 K-steps, converted once
    bf16x8 af[4];
#pragma unroll
    for (int ks = 0; ks < 4; ++ks) {
        float4 a0 = *reinterpret_cast<const float4*>(xp + ks * 32);
        float4 a1 = *reinterpret_cast<const float4*>(xp + ks * 32 + 4);
        uint* u = reinterpret_cast<uint*>(&af[ks]);
        u[0] = pack2_bf16(a0.x, a0.y); u[1] = pack2_bf16(a0.z, a0.w);
        u[2] = pack2_bf16(a1.x, a1.y); u[3] = pack2_bf16(a1.z, a1.w);
    }

    f32x4 acc[8];
#pragma unroll
    for (int ct = 0; ct < 8; ++ct) acc[ct] = (f32x4){0.f, 0.f, 0.f, 0.f};

#pragma unroll
    for (int ks = 0; ks < 4; ++ks) {
#pragma unroll
        for (int ct = 0; ct < 8; ++ct) {
            bf16x8 bf = *reinterpret_cast<const bf16x8*>(
                W + (ct * 16 + ml) * 128 + ks * 32 + quad * 8);
            acc[ct] = __builtin_amdgcn_mfma_f32_16x16x32_bf16(af[ks], bf, acc[ct], 0, 0, 0);
        }
    }

#pragma unroll
    for (int ct = 0; ct < 8; ++ct) {
        int col = ct * 16 + ml;
        float b = bias[col];
#pragma unroll
        for (int r = 0; r < 4; ++r) {
            int row = m0 + quad * 4 + r;
            if (row < N_NODES)
                C[row * 128 + col] = cvt_bf16(acc[ct][r] + b);
        }
    }
}

// ---------------------------------------------------------------------------
// Fused attention + output projection (R8 structure: 4 nodes/block, shared
// 16-row agg tile, 4-way split MFMA epilogue) with a 2-DEEP SOFTWARE
// PIPELINE in the gather loop: csr pairs fetched two batches ahead, K/V/bias
// one batch ahead via explicit register rotate. Batch i+1's gathers are
// issued from an already-resident csr pair BEFORE batch i's VALU, so their
// latency hides under compute + co-resident waves instead of being fully
// exposed each iteration. (R6's failed variant bound 2 edges/lane and let
// the compiler serialize 8 up-front loads; this keeps 1 edge/lane.)
// ---------------------------------------------------------------------------
__global__ __launch_bounds__(256) void fused_attn_out(
    const ushort* __restrict__ Q2, const ushort* __restrict__ K2,
    const ushort* __restrict__ V2,
    const float* __restrict__ attn_bias,
    const int* __restrict__ deg, const int2* __restrict__ csr2,
    const ushort* __restrict__ Wo2, const float* __restrict__ bo,
    float* __restrict__ logits, float* __restrict__ out)
{
    __shared__ ushort agg_sh[16 * 136];   // 16 rows x 136 ushorts (272B stride)

    const int tid  = threadIdx.x;
    const int lane = tid & 63;
    const int wid  = tid >> 6;
    const int n0 = blockIdx.x * 4;
    const int n  = n0 + wid;
    int dg = deg[n]; if (dg > MAXDEG) dg = MAXDEG;
    const int start = n * MAXDEG;
    const int h  = lane & 7;
    const int es = lane >> 3;
    const int ml   = lane & 15;
    const int quad = lane >> 4;

    // zero rows 4..15 of agg_sh (disjoint from rows 0..3 written below)
    if (tid < 204)
        *reinterpret_cast<uint4*>(reinterpret_cast<char*>(agg_sh) + 1088 + tid * 16) =
            make_uint4(0u, 0u, 0u, 0u);

    const uint4* Qu4 = reinterpret_cast<const uint4*>(Q2);
    const uint4* Ku4 = reinterpret_cast<const uint4*>(K2);
    const uint4* Vu4 = reinterpret_cast<const uint4*>(V2);

    // Q[n, h*16 .. +16) -> 16 floats (broadcast across the 8 e_slots)
    uint4 qa = Qu4[n * 16 + h * 2];
    uint4 qb = Qu4[n * 16 + h * 2 + 1];
    float qf[16];
    {
        uint qq[8] = {qa.x, qa.y, qa.z, qa.w, qb.x, qb.y, qb.z, qb.w};
#pragma unroll
        for (int j = 0; j < 8; ++j) {
            qf[2 * j]     = bf16_lo(qq[j]);
            qf[2 * j + 1] = bf16_hi(qq[j]);
        }
    }

    float acc[16];
#pragma unroll
    for (int j = 0; j < 16; ++j) acc[j] = 0.f;
    float z = 0.f;

    if (dg > 0) {
        // ---- pipeline prologue: csr(0), csr(1), then K/V/bias(0) ----
        int i0 = (es < dg) ? es : dg - 1;
        int2 ep0 = csr2[start + i0];
        int2 ep1;
        bool have1 = 8 < dg;
        if (have1) {
            int t1 = 8 + es; if (t1 >= dg) t1 = dg - 1;
            ep1 = csr2[start + t1];
        }
        uint4 ck0 = Ku4[ep0.y * 16 + h * 2];
        uint4 ck1 = Ku4[ep0.y * 16 + h * 2 + 1];
        uint4 cv0 = Vu4[ep0.y * 16 + h * 2];
        uint4 cv1 = Vu4[ep0.y * 16 + h * 2 + 1];
        float cb  = attn_bias[ep0.x * 8 + h];
        int   ce  = ep0.x;

        for (int base = 0; base < dg; base += 8) {
            const bool more = (base + 8) < dg;      // wave-uniform

            // issue next batch's K/V/bias from the resident csr pair ep1
            uint4 nk0, nk1, nv0, nv1; float nb = 0.f; int ne = 0;
            if (more) {
                nk0 = Ku4[ep1.y * 16 + h * 2];
                nk1 = Ku4[ep1.y * 16 + h * 2 + 1];
                nv0 = Vu4[ep1.y * 16 + h * 2];
                nv1 = Vu4[ep1.y * 16 + h * 2 + 1];
                nb  = attn_bias[ep1.x * 8 + h];
                ne  = ep1.x;
            }
            // refill csr two batches ahead
            if ((base + 16) < dg) {
                int t2 = base + 16 + es; if (t2 >= dg) t2 = dg - 1;
                ep1 = csr2[start + t2];
            }

            // ---- compute current batch from resident registers ----
            bool valid = (base + es) < dg;
            uint kk[8] = {ck0.x, ck0.y, ck0.z, ck0.w, ck1.x, ck1.y, ck1.z, ck1.w};
            float d = 0.f;
#pragma unroll
            for (int j = 0; j < 8; ++j)
                d += qf[2 * j] * bf16_lo(kk[j]) + qf[2 * j + 1] * bf16_hi(kk[j]);

            float l = 0.25f * d + cb;
            float p = 0.f;
            if (valid) {
                __builtin_nontemporal_store(l, &logits[ce * 8 + h]);
                p = __expf(l);
            }
            z += p;

            uint vv[8] = {cv0.x, cv0.y, cv0.z, cv0.w, cv1.x, cv1.y, cv1.z, cv1.w};
#pragma unroll
            for (int j = 0; j < 8; ++j) {
                acc[2 * j]     += p * bf16_lo(vv[j]);
                acc[2 * j + 1] += p * bf16_hi(vv[j]);
            }

            // ---- rotate pipeline registers ----
            if (more) {
                ck0 = nk0; ck1 = nk1; cv0 = nv0; cv1 = nv1; cb = nb; ce = ne;
            }
        }
    }

    // reduce-scatter butterfly over e_slot bits (lane bits 5,4,3)
    {
        int bit = (lane >> 5) & 1;
#pragma unroll
        for (int j = 0; j < 8; ++j) {
            float send = bit ? acc[j] : acc[j + 8];
            float keep = bit ? acc[j + 8] : acc[j];
            acc[j] = keep + __shfl_xor(send, 32, 64);
        }
        bit = (lane >> 4) & 1;
#pragma unroll
        for (int j = 0; j < 4; ++j) {
            float send = bit ? acc[j] : acc[j + 4];
            float keep = bit ? acc[j + 4] : acc[j];
            acc[j] = keep + __shfl_xor(send, 16, 64);
        }
        bit = (lane >> 3) & 1;
#pragma unroll
        for (int j = 0; j < 2; ++j) {
            float send = bit ? acc[j] : acc[j + 2];
            float keep = bit ? acc[j + 2] : acc[j];
            acc[j] = keep + __shfl_xor(send, 8, 64);
        }
    }
    z += __shfl_xor(z, 8, 64);
    z += __shfl_xor(z, 16, 64);
    z += __shfl_xor(z, 32, 64);

    float inv = (z > 0.f) ? 1.f / z : 0.f;
    // lane holds output dims h*16 + d_off + {0,1}; write bf16 pair to LDS
    int d_off = ((lane >> 5) & 1) * 8 + ((lane >> 4) & 1) * 4 + ((lane >> 3) & 1) * 2;
    *reinterpret_cast<uint*>(reinterpret_cast<char*>(agg_sh) + wid * 272 +
                             (h * 16 + d_off) * 2) =
        pack2_bf16(acc[0] * inv, acc[1] * inv);

    __syncthreads();

    // ---- all 4 waves: output projection, 2 column-tiles (32 cols) each ----
    {
        bf16x8 af[4];
#pragma unroll
        for (int ks = 0; ks < 4; ++ks)
            af[ks] = *reinterpret_cast<const bf16x8*>(
                reinterpret_cast<char*>(agg_sh) + ml * 272 + ks * 64 + quad * 16);

        f32x4 oacc[2];
        oacc[0] = (f32x4){0.f, 0.f, 0.f, 0.f};
        oacc[1] = (f32x4){0.f, 0.f, 0.f, 0.f};

#pragma unroll
        for (int ks = 0; ks < 4; ++ks) {
#pragma unroll
            for (int c = 0; c < 2; ++c) {
                bf16x8 bf = *reinterpret_cast<const bf16x8*>(
                    Wo2 + ((wid * 2 + c) * 16 + ml) * 128 + ks * 32 + quad * 8);
                oacc[c] = __builtin_amdgcn_mfma_f32_16x16x32_bf16(af[ks], bf, oacc[c], 0, 0, 0);
            }
        }

        if (quad == 0) {   // rows 0..3 = the block's 4 nodes
#pragma unroll
            for (int c = 0; c < 2; ++c) {
                int col = (wid * 2 + c) * 16 + ml;
                float b = bo[col];
#pragma unroll
                for (int r = 0; r < 4; ++r)
                    out[(n0 + r) * 128 + col] = oacc[c][r] + b;
            }
        }
    }
}

// ---------------------------------------------------------------------------
extern "C" void kernel_launch(void* const* d_in, const int* in_sizes, int n_in,
                              void* d_out, int out_size, void* d_ws, size_t ws_size,
                              hipStream_t stream)
{
    const float* x         = (const float*)d_in[0];
    const int*   ei        = (const int*)  d_in[1];
    const float* attn_bias = (const float*)d_in[2];
    const float* Wq = (const float*)d_in[3];
    const float* bq = (const float*)d_in[4];
    const float* Wk = (const float*)d_in[5];
    const float* bk = (const float*)d_in[6];
    const float* Wv = (const float*)d_in[7];
    const float* bv = (const float*)d_in[8];
    const float* Wo = (const float*)d_in[9];
    const float* bo = (const float*)d_in[10];

    float* out    = (float*)d_out;                // [N,128]
    float* logits = out + N_NODES * EMBED;        // [E,8] (output 1)

    ushort* wb   = (ushort*)d_ws;                 // 4*16384 (Wq,Wk,Wv,Wo)
    ushort* Qb   = wb + 4 * 16384;                // N*128
    ushort* Kb   = Qb + NX;                       // N*128
    ushort* Vb   = Kb + NX;                       // N*128
    int* deg     = (int*)(Vb + NX);               // N (doubles as append cursor)
    int2* csr2   = (int2*)(deg + N_NODES);        // N*MAXDEG pairs {edge, src}

    prep<<<128, 256, 0, stream>>>(Wq, Wk, Wv, Wo, wb, deg);

    gemm_qkv_scatter<<<TOT_BLK, 256, 0, stream>>>(
        x, wb, bq, bk, bv, Qb, Kb, Vb, ei, deg, csr2);

    fused_attn_out<<<N_NODES / 4, 256, 0, stream>>>(Qb, Kb, Vb, attn_bias,
                                                    deg, csr2, wb + 3 * 16384,
                                                    bo, logits, out);
}